// Round 1
// 1434.983 us; speedup vs baseline: 1.1555x; 1.1555x over previous
//
#include <hip/hip_runtime.h>
#include <math.h>

namespace {

constexpr int Bb = 16;
constexpr int TQ = 2048;
constexpr int TK = 2048;
constexpr int D  = 1024;

typedef __bf16 bf16x8 __attribute__((ext_vector_type(8)));
typedef float  f32x4  __attribute__((ext_vector_type(4)));
typedef unsigned short u16;
typedef unsigned int   u32;
typedef u16 u16x8 __attribute__((ext_vector_type(8)));

typedef __attribute__((address_space(1))) const unsigned char gbyte;
typedef __attribute__((address_space(3))) unsigned char sbyte;

__device__ inline u16 f2bf(float f) {
    u32 u = __builtin_bit_cast(u32, f);
    u += 0x7fffu + ((u >> 16) & 1u);          // round-to-nearest-even
    return (u16)(u >> 16);
}
__device__ inline float bf2f(u16 h) {
    u32 u = (u32)h << 16;
    return __builtin_bit_cast(float, u);
}
__device__ inline void split1(float f, u16& h, u16& l) {
    h = f2bf(f);
    l = f2bf(f - bf2f(h));
}

__device__ inline void gload16(const void* g, void* l) {
    __builtin_amdgcn_global_load_lds((gbyte*)g, (sbyte*)l, 16, 0, 0);
}

// ---------------------------------------------------------------------------
// Deep-pipelined NT GEMM: C[m][n] = sum_k A[m][k]*B[n][k], bf16 in, fp32 acc.
// 256x256 tile, BK=32, 512 thr = 8 waves (2M x 4N), each wave owns 128x64.
// 4-deep LDS ring (4 x (16KB A + 16KB B) = 128 KiB) staged by
// global_load_lds dwordx4 with counted vmcnt(4) (never drained to 0 in the
// main loop).  Two phases per K-tile:
//   {ds_read frags | issue 2 gload_lds -> s_barrier -> setprio(1) ->
//    16 MFMA -> setprio(0) -> s_barrier}
// LDS 16B slots are XOR-swizzled (slot ^= (row>>1)&3) via pre-swizzled
// GLOBAL source addresses (LDS dest stays linear, as global_load_lds needs).
// SEGS==3: bf16x3 product -- K-space = 3 segments over [M][2K]/[N][2K]:
//   seg0: Ah*Bh (Aoff=0,Boff=0)  seg1: Ah*Bl (0,K)  seg2: Al*Bh (K,0)
// EPI==0: store fp32.  EPI==1: split h/l store into C2 [M][2N].
// ---------------------------------------------------------------------------

template<bool STAGE, int VM>
__device__ __attribute__((always_inline))
void tile_pair(const char* At, const char* Bt, char* stA, char* stB,
               const u16* a0, const u16* a1, const u16* b0, const u16* b1,
               int aRd, int bRd, f32x4 (&acc)[8][4])
{
    bf16x8 afr[4], bfr[4];
    // ---- phase 0: m-half 0, all 4 n-frags ----
    #pragma unroll
    for (int mt = 0; mt < 4; ++mt)
        afr[mt] = *(const bf16x8*)(At + aRd + mt * 1024);
    #pragma unroll
    for (int nt = 0; nt < 4; ++nt)
        bfr[nt] = *(const bf16x8*)(Bt + bRd + nt * 1024);
    if constexpr (STAGE) {
        gload16(a0, stA);            // A rows   0..127 of tile t+2
        gload16(a1, stA + 8192);     // A rows 128..255
    }
    __builtin_amdgcn_s_barrier();
    __builtin_amdgcn_s_setprio(1);
    #pragma unroll
    for (int mt = 0; mt < 4; ++mt)
        #pragma unroll
        for (int nt = 0; nt < 4; ++nt)
            acc[mt][nt] = __builtin_amdgcn_mfma_f32_16x16x32_bf16(
                afr[mt], bfr[nt], acc[mt][nt], 0, 0, 0);
    __builtin_amdgcn_s_setprio(0);
    __builtin_amdgcn_s_barrier();
    // ---- phase 1: m-half 1, reuse B frags ----
    #pragma unroll
    for (int mt = 0; mt < 4; ++mt)
        afr[mt] = *(const bf16x8*)(At + aRd + 4096 + mt * 1024);
    if constexpr (STAGE) {
        gload16(b0, stB);            // B rows   0..127 of tile t+2
        gload16(b1, stB + 8192);     // B rows 128..255
    }
    __builtin_amdgcn_s_barrier();
    __builtin_amdgcn_s_setprio(1);
    #pragma unroll
    for (int mt = 0; mt < 4; ++mt)
        #pragma unroll
        for (int nt = 0; nt < 4; ++nt)
            acc[4 + mt][nt] = __builtin_amdgcn_mfma_f32_16x16x32_bf16(
                afr[mt], bfr[nt], acc[4 + mt][nt], 0, 0, 0);
    __builtin_amdgcn_s_setprio(0);
    // end-of-tile wait: leave the 4 loads of tile t+2 in flight (T4)
    if constexpr (VM == 4)      asm volatile("s_waitcnt vmcnt(4)" ::: "memory");
    else if constexpr (VM == 0) asm volatile("s_waitcnt vmcnt(0)" ::: "memory");
    __builtin_amdgcn_s_barrier();
}

template<int SEGS, int EPI>
__global__ __launch_bounds__(512, 2)
void gemm_nt_pipe(const u16* __restrict__ A, const u16* __restrict__ B,
                  float* __restrict__ Cf, u16* __restrict__ C2,
                  int M, int N, int K,
                  long long sA, long long sB, long long sC)
{
    __shared__ char lds[131072];   // 4 ring slots x (A 16K | B 16K)

    const int tid  = threadIdx.x;
    const int lane = tid & 63;
    const int wave = tid >> 6;
    const int wm   = wave >> 2;            // 0..1  (M half)
    const int wn   = wave & 3;             // 0..3  (N quarter)
    const int lr   = lane & 15;
    const int lq   = lane >> 4;

    const int n0 = blockIdx.x * 256;
    const int m0 = blockIdx.y * 256;
    const int bz = blockIdx.z;

    const int ld = (SEGS == 3) ? 2 * K : K;     // row stride (elements)

    const u16* Ab  = A + (long long)bz * sA;
    const u16* Bbp = B + (long long)bz * sB;

    // --- staging source (pre-swizzled 16B slot so LDS dest stays linear) ---
    const int srow = tid >> 2;                       // 0..127
    const int scol = (tid & 3) ^ ((tid >> 3) & 3);   // slot ^ ((row>>1)&3)
    const u16* aS0 = Ab  + (long long)(m0 + srow) * ld + scol * 8;
    const u16* aS1 = aS0 + (long long)128 * ld;
    const u16* bS0 = Bbp + (long long)(n0 + srow) * ld + scol * 8;
    const u16* bS1 = bS0 + (long long)128 * ld;

    char* const stBase = lds;
    const int stW = wave * 1024;   // per-wave uniform LDS stage base offset

    // --- LDS read offsets (same XOR on the read side) ---
    const int slotswz = (lq ^ ((lr >> 1) & 3)) << 4;
    const int aRd = (wm * 128 + lr) * 64 + slotswz;
    const int bRd = (wn * 64  + lr) * 64 + slotswz;

    f32x4 acc[8][4];
    #pragma unroll
    for (int i = 0; i < 8; ++i)
        #pragma unroll
        for (int j = 0; j < 4; ++j)
            acc[i][j] = (f32x4){0.f, 0.f, 0.f, 0.f};

    const int NT = (SEGS == 3 ? 3 * K : K) / 32;

    // staging k-state (tracks the tile currently being staged)
    int kloc = 0, seg = 0;

    // ---- prologue: stage ring slots 0 and 1 (8 loads), wait for tile 0 ----
    #pragma unroll
    for (int p = 0; p < 2; ++p) {
        const int ao = kloc + ((SEGS == 3 && seg == 2) ? K : 0);
        const int bo = kloc + ((SEGS == 3 && seg == 1) ? K : 0);
        char* tb = stBase + p * 32768;
        gload16(aS0 + ao, tb + stW);
        gload16(aS1 + ao, tb + 8192 + stW);
        gload16(bS0 + bo, tb + 16384 + stW);
        gload16(bS1 + bo, tb + 16384 + 8192 + stW);
        kloc += 32;
        if (SEGS == 3 && kloc == K) { kloc = 0; ++seg; }
    }
    asm volatile("s_waitcnt vmcnt(4)" ::: "memory");   // tile 0 ready
    __builtin_amdgcn_s_barrier();

    // ---- steady state: compute tile t, stage tile t+2 ----
    for (int t = 0; t < NT - 2; ++t) {
        const char* At = stBase + (t & 3) * 32768;
        char* st = stBase + ((t + 2) & 3) * 32768;
        const int ao = kloc + ((SEGS == 3 && seg == 2) ? K : 0);
        const int bo = kloc + ((SEGS == 3 && seg == 1) ? K : 0);
        tile_pair<true, 4>(At, At + 16384, st + stW, st + 16384 + stW,
                           aS0 + ao, aS1 + ao, bS0 + bo, bS1 + bo,
                           aRd, bRd, acc);
        kloc += 32;
        if (SEGS == 3 && kloc == K) { kloc = 0; ++seg; }
    }
    {   // tile NT-2: nothing left to stage; drain remaining 4 loads
        const char* At = stBase + ((NT - 2) & 3) * 32768;
        tile_pair<false, 0>(At, At + 16384, nullptr, nullptr,
                            nullptr, nullptr, nullptr, nullptr, aRd, bRd, acc);
    }
    {   // tile NT-1
        const char* At = stBase + ((NT - 1) & 3) * 32768;
        tile_pair<false, -1>(At, At + 16384, nullptr, nullptr,
                             nullptr, nullptr, nullptr, nullptr, aRd, bRd, acc);
    }

    // ---- epilogue: C/D layout row=(lane>>4)*4+reg, col=lane&15 ----
    if constexpr (EPI == 0) {
        #pragma unroll
        for (int mt = 0; mt < 8; ++mt) {
            const int row = m0 + wm * 128 + mt * 16 + lq * 4;
            #pragma unroll
            for (int nt = 0; nt < 4; ++nt) {
                const int col = n0 + wn * 64 + nt * 16 + lr;
                #pragma unroll
                for (int rg = 0; rg < 4; ++rg)
                    Cf[(long long)bz * sC + (long long)(row + rg) * N + col] =
                        acc[mt][nt][rg];
            }
        }
    } else {
        #pragma unroll
        for (int mt = 0; mt < 8; ++mt) {
            const int row = m0 + wm * 128 + mt * 16 + lq * 4;
            #pragma unroll
            for (int nt = 0; nt < 4; ++nt) {
                const int col = n0 + wn * 64 + nt * 16 + lr;
                #pragma unroll
                for (int rg = 0; rg < 4; ++rg) {
                    const long long base =
                        (long long)bz * sC + (long long)(row + rg) * (2 * N);
                    u16 h, l;
                    split1(acc[mt][nt][rg], h, l);
                    C2[base + col]     = h;
                    C2[base + N + col] = l;
                }
            }
        }
    }
}

// ---------------------------------------------------------------------------
// fp32 [R][1024] -> bf16 [R][2048]  (h in cols 0..1023, l in 1024..2047)
// ---------------------------------------------------------------------------
__global__ __launch_bounds__(256)
void split_rows(const float* __restrict__ in, u16* __restrict__ out)
{
    const long long i = (long long)blockIdx.x * 256 + threadIdx.x; // 8-chunk id
    const long long row = i >> 7;              // 128 chunks / row
    const int c = ((int)i & 127) << 3;
    const float* p = in + row * 1024 + c;
    float4 v0 = *(const float4*)p;
    float4 v1 = *(const float4*)(p + 4);
    float x[8] = {v0.x, v0.y, v0.z, v0.w, v1.x, v1.y, v1.z, v1.w};
    u16x8 h, l;
    #pragma unroll
    for (int j = 0; j < 8; ++j) {
        u16 hh, lo;
        split1(x[j], hh, lo);
        h[j] = hh; l[j] = lo;
    }
    u16* q = out + row * 2048 + c;
    *(u16x8*)q = h;
    *(u16x8*)(q + 1024) = l;
}

// ---------------------------------------------------------------------------
// Transpose fp32 [R][C] -> bf16 [C][R] (hi only). 32x32 tiles.
// ---------------------------------------------------------------------------
__global__ __launch_bounds__(256)
void transpose_h(const float* __restrict__ in, u16* __restrict__ outh,
                 int R, int C, long long sIn, long long sOut)
{
    __shared__ float t[32][33];
    const int bz = blockIdx.z;
    const int c0 = blockIdx.x * 32;
    const int r0 = blockIdx.y * 32;
    const float* inb = in + (long long)bz * sIn;
    const int tid = threadIdx.x;
    #pragma unroll
    for (int i = 0; i < 4; ++i) {
        int e = i * 256 + tid;
        int r = e >> 5, c = e & 31;
        t[r][c] = inb[(long long)(r0 + r) * C + c0 + c];
    }
    __syncthreads();
    #pragma unroll
    for (int i = 0; i < 4; ++i) {
        int e = i * 256 + tid;
        int r = e >> 5, c = e & 31;
        outh[(long long)bz * sOut + (long long)(c0 + r) * R + r0 + c] =
            f2bf(t[c][r]);
    }
}

// ---------------------------------------------------------------------------
// W [D][D] fp32 -> Wt2 [D][2D] bf16: h at [e][d], l at [e][D+d]
// ---------------------------------------------------------------------------
__global__ __launch_bounds__(256)
void transpose_split2(const float* __restrict__ in, u16* __restrict__ out2)
{
    __shared__ float t[32][33];
    const int c0 = blockIdx.x * 32;
    const int r0 = blockIdx.y * 32;
    const int tid = threadIdx.x;
    #pragma unroll
    for (int i = 0; i < 4; ++i) {
        int e = i * 256 + tid;
        int r = e >> 5, c = e & 31;
        t[r][c] = in[(long long)(r0 + r) * D + c0 + c];
    }
    __syncthreads();
    #pragma unroll
    for (int i = 0; i < 4; ++i) {
        int e = i * 256 + tid;
        int r = e >> 5, c = e & 31;
        u16 h, l;
        split1(t[c][r], h, l);
        const long long off = (long long)(c0 + r) * (2 * D) + r0 + c;
        out2[off]     = h;
        out2[off + D] = l;
    }
}

// ---------------------------------------------------------------------------
// Row softmax in place + bf16 copy: one block per row of TK floats.
// ---------------------------------------------------------------------------
__global__ __launch_bounds__(256)
void softmax_kernel(float* __restrict__ S, u16* __restrict__ Sb)
{
    __shared__ float red[4];
    const long long row = blockIdx.x;
    float* p = S + row * (long long)TK;
    const int tid = threadIdx.x;

    float x[8];
    *(float4*)&x[0] = *(const float4*)(p + tid * 8);
    *(float4*)&x[4] = *(const float4*)(p + tid * 8 + 4);

    float mx = x[0];
    #pragma unroll
    for (int i = 1; i < 8; ++i) mx = fmaxf(mx, x[i]);
    #pragma unroll
    for (int off = 32; off > 0; off >>= 1) mx = fmaxf(mx, __shfl_down(mx, off, 64));
    if ((tid & 63) == 0) red[tid >> 6] = mx;
    __syncthreads();
    mx = fmaxf(fmaxf(red[0], red[1]), fmaxf(red[2], red[3]));
    __syncthreads();

    float s = 0.f;
    #pragma unroll
    for (int i = 0; i < 8; ++i) { x[i] = __expf(x[i] - mx); s += x[i]; }
    #pragma unroll
    for (int off = 32; off > 0; off >>= 1) s += __shfl_down(s, off, 64);
    if ((tid & 63) == 0) red[tid >> 6] = s;
    __syncthreads();
    s = red[0] + red[1] + red[2] + red[3];

    const float inv = 1.f / s;
    #pragma unroll
    for (int i = 0; i < 8; ++i) x[i] *= inv;
    *(float4*)(p + tid * 8)     = *(const float4*)&x[0];
    *(float4*)(p + tid * 8 + 4) = *(const float4*)&x[4];

    u16x8 hb;
    #pragma unroll
    for (int i = 0; i < 8; ++i) hb[i] = f2bf(x[i]);
    *(u16x8*)(Sb + row * (long long)TK + tid * 8) = hb;
}

} // anonymous namespace

extern "C" void kernel_launch(void* const* d_in, const int* in_sizes, int n_in,
                              void* d_out, int out_size, void* d_ws, size_t ws_size,
                              hipStream_t stream)
{
    typedef long long ll;
    const float* dec = (const float*)d_in[0];  // [B, TQ, D]
    const float* enc = (const float*)d_in[1];  // [B, TK, D]
    const float* W   = (const float*)d_in[2];  // [D, D]
    // d_in[3] = bias: contributes dec[q].bias, constant along the softmax
    // axis -> cancels exactly in softmax; neither output depends on it.

    float* out     = (float*)d_out;
    float* context = out;                      // [B, TQ, D]
    float* align   = out + (ll)Bb * TQ * D;    // [B, TQ, TK]

    // workspace (u16): dec2 [B][TQ][2D] | keys2 [B][TK][2D] | Wt2 [D][2D]
    u16* dec2   = (u16*)d_ws;
    u16* keys2  = dec2 + (ll)Bb * TQ * 2 * D;
    u16* Wt2    = keys2 + (ll)Bb * TK * 2 * D;
    // scratch aliases (lifetimes verified against launch order):
    u16* enc2   = (u16*)align;   // enc split lives in align region until score
    u16* encT   = dec2;          // [B][D][TK]; dec2 dead after score
    u16* alignb = keys2;         // [B][TQ][TK] bf16; keys2 dead after score

    dim3 blk256(256);
    dim3 blk512(512);

    // 1) dec2 = split(dec)
    split_rows<<<dim3(Bb * TQ * D / 8 / 256), blk256, 0, stream>>>(dec, dec2);
    // 2) enc2 = split(enc)  (scratch in align output region)
    split_rows<<<dim3(Bb * TK * D / 8 / 256), blk256, 0, stream>>>(enc, enc2);
    // 3) Wt2 = split(W^T)
    transpose_split2<<<dim3(D / 32, D / 32, 1), blk256, 0, stream>>>(W, Wt2);
    // 4) keys2 = split(enc @ W)   (bf16x3, split-store epilogue)
    gemm_nt_pipe<3, 1><<<dim3(D / 256, TK / 256, Bb), blk512, 0, stream>>>(
        enc2, Wt2, nullptr, keys2, TK, D, D,
        (ll)TK * 2 * D, 0LL, (ll)TK * 2 * D);
    // 5) score = dec @ keys^T  (bf16x3) -> align region, fp32
    gemm_nt_pipe<3, 0><<<dim3(TK / 256, TQ / 256, Bb), blk512, 0, stream>>>(
        dec2, keys2, align, nullptr, TQ, TK, D,
        (ll)TQ * 2 * D, (ll)TK * 2 * D, (ll)TQ * TK);
    // 6) encT = enc^T bf16 (into dec2 space)
    transpose_h<<<dim3(D / 32, TK / 32, Bb), blk256, 0, stream>>>(
        enc, encT, TK, D, (ll)TK * D, (ll)D * TK);
    // 7) softmax in place + bf16 copy into alignb (keys2 space)
    softmax_kernel<<<dim3(Bb * TQ), blk256, 0, stream>>>(align, alignb);
    // 8) context = align @ enc  (plain bf16)
    gemm_nt_pipe<1, 0><<<dim3(D / 256, TQ / 256, Bb), blk512, 0, stream>>>(
        alignb, encT, context, nullptr, TQ, D, TK,
        (ll)TQ * TK, (ll)D * TK, (ll)TQ * D);
}

// Round 2
// 1385.050 us; speedup vs baseline: 1.1971x; 1.0361x over previous
//
#include <hip/hip_runtime.h>
#include <math.h>

namespace {

constexpr int Bb = 16;
constexpr int TQ = 2048;
constexpr int TK = 2048;
constexpr int D  = 1024;

typedef __bf16 bf16x8 __attribute__((ext_vector_type(8)));
typedef float  f32x4  __attribute__((ext_vector_type(4)));
typedef unsigned short u16;
typedef unsigned int   u32;
typedef u16 u16x8 __attribute__((ext_vector_type(8)));

typedef __attribute__((address_space(1))) const unsigned char gbyte;
typedef __attribute__((address_space(3))) unsigned char sbyte;

__device__ inline u16 f2bf(float f) {
    u32 u = __builtin_bit_cast(u32, f);
    u += 0x7fffu + ((u >> 16) & 1u);          // round-to-nearest-even
    return (u16)(u >> 16);
}
__device__ inline float bf2f(u16 h) {
    u32 u = (u32)h << 16;
    return __builtin_bit_cast(float, u);
}
__device__ inline void split1(float f, u16& h, u16& l) {
    h = f2bf(f);
    l = f2bf(f - bf2f(h));
}

__device__ inline void gload16(const void* g, void* l) {
    __builtin_amdgcn_global_load_lds((gbyte*)g, (sbyte*)l, 16, 0, 0);
}

#define MFMA16(d, a, b) d = __builtin_amdgcn_mfma_f32_16x16x32_bf16(a, b, d, 0, 0, 0)

// ---------------------------------------------------------------------------
// 8-phase deep-pipelined NT GEMM: C[m][n] = sum_k A[m][k]*B[n][k], bf16 in.
// 256x256 tile, BK=64, 512 thr = 8 waves (2M x 4N), wave owns 128x64 out.
// LDS: 2 buffers x (A[256][64] | B[256][64]) bf16 = 128 KiB.
// Per K-tile: 4 phases, each {ds_read subtile | issue 2 global_load_lds ->
//   s_barrier -> lgkmcnt(0) -> setprio(1) -> 16 MFMA -> setprio(0) -> bar}.
// Staging order for tile t+1 (2 issues/phase): A0,A2 | B0,B1 | B2,B3 | A1,A3.
// Counted waits (T4, never 0 in steady state):
//   vmcnt(4) end of phase 1  (A1,A3 of tile t land; 4 of t+1 in flight)
//   vmcnt(2) end of phase 3  (first-6 of t+1 land; its A1,A3 in flight)
// Rows are 64 bf16 = 8 x 16B slots; slot ^= (row&7) swizzle applied on the
// pre-swizzled GLOBAL source (LDS dest linear for global_load_lds) and on
// the ds_read address -> conflict-free (measured 0 conflicts with this
// scheme at BK=32).
// SEGS==3: bf16x3 product, K-space = 3 segments over [M][2K]/[N][2K]:
//   seg0 Ah*Bh (0,0)  seg1 Ah*Bl (0,K)  seg2 Al*Bh (K,0)
// EPI==0: fp32 store.  EPI==1: split h/l store into C2 [M][2N].
// ---------------------------------------------------------------------------
template<bool STAGE>
__device__ __attribute__((always_inline))
void do_tile(const char* buf, char* nA, char* nB,
             const u16* aP, const u16* bP, long long ld64,
             int aRd, int bRd, f32x4 (&acc)[8][4])
{
    bf16x8 B0,B1,B2,B3,B4,B5,B6,B7, A0,A1,A2,A3;

    // ===== phase 0: read all B + A(mt0,1); stage A0,A2 of t+1 =====
    A0 = *(const bf16x8*)(buf + aRd);
    A1 = *(const bf16x8*)(buf + (aRd ^ 64));
    A2 = *(const bf16x8*)(buf + aRd + 2048);
    A3 = *(const bf16x8*)(buf + (aRd ^ 64) + 2048);
    B0 = *(const bf16x8*)(buf + bRd);
    B1 = *(const bf16x8*)(buf + (bRd ^ 64));
    B2 = *(const bf16x8*)(buf + bRd + 2048);
    B3 = *(const bf16x8*)(buf + (bRd ^ 64) + 2048);
    B4 = *(const bf16x8*)(buf + bRd + 4096);
    B5 = *(const bf16x8*)(buf + (bRd ^ 64) + 4096);
    B6 = *(const bf16x8*)(buf + bRd + 6144);
    B7 = *(const bf16x8*)(buf + (bRd ^ 64) + 6144);
    if constexpr (STAGE) {
        gload16(aP,              nA);            // A0 rows   0- 63
        gload16(aP + 2 * ld64,   nA + 16384);    // A2 rows 128-191
    }
    asm volatile("s_waitcnt lgkmcnt(8)" ::: "memory");
    __builtin_amdgcn_s_barrier();
    asm volatile("s_waitcnt lgkmcnt(0)" ::: "memory");
    __builtin_amdgcn_s_setprio(1);
    MFMA16(acc[0][0], A0, B0); MFMA16(acc[0][1], A0, B2);
    MFMA16(acc[0][2], A0, B4); MFMA16(acc[0][3], A0, B6);
    MFMA16(acc[1][0], A2, B0); MFMA16(acc[1][1], A2, B2);
    MFMA16(acc[1][2], A2, B4); MFMA16(acc[1][3], A2, B6);
    MFMA16(acc[0][0], A1, B1); MFMA16(acc[0][1], A1, B3);
    MFMA16(acc[0][2], A1, B5); MFMA16(acc[0][3], A1, B7);
    MFMA16(acc[1][0], A3, B1); MFMA16(acc[1][1], A3, B3);
    MFMA16(acc[1][2], A3, B5); MFMA16(acc[1][3], A3, B7);
    __builtin_amdgcn_s_setprio(0);
    __builtin_amdgcn_s_barrier();

    // ===== phase 1: read A(mt2,3); stage B0,B1 of t+1 =====
    A0 = *(const bf16x8*)(buf + aRd + 4096);
    A1 = *(const bf16x8*)(buf + (aRd ^ 64) + 4096);
    A2 = *(const bf16x8*)(buf + aRd + 6144);
    A3 = *(const bf16x8*)(buf + (aRd ^ 64) + 6144);
    if constexpr (STAGE) {
        gload16(bP,        nB);                  // B0 rows   0- 63
        gload16(bP + ld64, nB + 8192);           // B1 rows  64-127
    }
    __builtin_amdgcn_s_barrier();
    asm volatile("s_waitcnt lgkmcnt(0)" ::: "memory");
    __builtin_amdgcn_s_setprio(1);
    MFMA16(acc[2][0], A0, B0); MFMA16(acc[2][1], A0, B2);
    MFMA16(acc[2][2], A0, B4); MFMA16(acc[2][3], A0, B6);
    MFMA16(acc[3][0], A2, B0); MFMA16(acc[3][1], A2, B2);
    MFMA16(acc[3][2], A2, B4); MFMA16(acc[3][3], A2, B6);
    MFMA16(acc[2][0], A1, B1); MFMA16(acc[2][1], A1, B3);
    MFMA16(acc[2][2], A1, B5); MFMA16(acc[2][3], A1, B7);
    MFMA16(acc[3][0], A3, B1); MFMA16(acc[3][1], A3, B3);
    MFMA16(acc[3][2], A3, B5); MFMA16(acc[3][3], A3, B7);
    __builtin_amdgcn_s_setprio(0);
    if constexpr (STAGE) asm volatile("s_waitcnt vmcnt(4)" ::: "memory");
    else                 asm volatile("s_waitcnt vmcnt(0)" ::: "memory");
    __builtin_amdgcn_s_barrier();

    // ===== phase 2: read A(mt4,5); stage B2,B3 of t+1 =====
    A0 = *(const bf16x8*)(buf + aRd + 8192);
    A1 = *(const bf16x8*)(buf + (aRd ^ 64) + 8192);
    A2 = *(const bf16x8*)(buf + aRd + 10240);
    A3 = *(const bf16x8*)(buf + (aRd ^ 64) + 10240);
    if constexpr (STAGE) {
        gload16(bP + 2 * ld64, nB + 16384);      // B2 rows 128-191
        gload16(bP + 3 * ld64, nB + 24576);      // B3 rows 192-255
    }
    __builtin_amdgcn_s_barrier();
    asm volatile("s_waitcnt lgkmcnt(0)" ::: "memory");
    __builtin_amdgcn_s_setprio(1);
    MFMA16(acc[4][0], A0, B0); MFMA16(acc[4][1], A0, B2);
    MFMA16(acc[4][2], A0, B4); MFMA16(acc[4][3], A0, B6);
    MFMA16(acc[5][0], A2, B0); MFMA16(acc[5][1], A2, B2);
    MFMA16(acc[5][2], A2, B4); MFMA16(acc[5][3], A2, B6);
    MFMA16(acc[4][0], A1, B1); MFMA16(acc[4][1], A1, B3);
    MFMA16(acc[4][2], A1, B5); MFMA16(acc[4][3], A1, B7);
    MFMA16(acc[5][0], A3, B1); MFMA16(acc[5][1], A3, B3);
    MFMA16(acc[5][2], A3, B5); MFMA16(acc[5][3], A3, B7);
    __builtin_amdgcn_s_setprio(0);
    __builtin_amdgcn_s_barrier();

    // ===== phase 3: read A(mt6,7); stage A1,A3 of t+1 =====
    A0 = *(const bf16x8*)(buf + aRd + 12288);
    A1 = *(const bf16x8*)(buf + (aRd ^ 64) + 12288);
    A2 = *(const bf16x8*)(buf + aRd + 14336);
    A3 = *(const bf16x8*)(buf + (aRd ^ 64) + 14336);
    if constexpr (STAGE) {
        gload16(aP + ld64,     nA + 8192);       // A1 rows  64-127
        gload16(aP + 3 * ld64, nA + 24576);      // A3 rows 192-255
    }
    __builtin_amdgcn_s_barrier();
    asm volatile("s_waitcnt lgkmcnt(0)" ::: "memory");
    __builtin_amdgcn_s_setprio(1);
    MFMA16(acc[6][0], A0, B0); MFMA16(acc[6][1], A0, B2);
    MFMA16(acc[6][2], A0, B4); MFMA16(acc[6][3], A0, B6);
    MFMA16(acc[7][0], A2, B0); MFMA16(acc[7][1], A2, B2);
    MFMA16(acc[7][2], A2, B4); MFMA16(acc[7][3], A2, B6);
    MFMA16(acc[6][0], A1, B1); MFMA16(acc[6][1], A1, B3);
    MFMA16(acc[6][2], A1, B5); MFMA16(acc[6][3], A1, B7);
    MFMA16(acc[7][0], A3, B1); MFMA16(acc[7][1], A3, B3);
    MFMA16(acc[7][2], A3, B5); MFMA16(acc[7][3], A3, B7);
    __builtin_amdgcn_s_setprio(0);
    if constexpr (STAGE) asm volatile("s_waitcnt vmcnt(2)" ::: "memory");
    __builtin_amdgcn_s_barrier();
}

template<int SEGS, int EPI>
__global__ __launch_bounds__(512, 2)
void gemm_nt_pipe(const u16* __restrict__ A, const u16* __restrict__ B,
                  float* __restrict__ Cf, u16* __restrict__ C2,
                  int M, int N, int K,
                  long long sA, long long sB, long long sC)
{
    __shared__ char lds[131072];   // 2 bufs x (A 32K | B 32K)

    const int tid  = threadIdx.x;
    const int lane = tid & 63;
    const int wave = tid >> 6;
    const int wm   = wave >> 2;            // 0..1  (M half)
    const int wn   = wave & 3;             // 0..3  (N quarter)
    const int lr   = lane & 15;
    const int lq   = lane >> 4;

    const int n0 = blockIdx.x * 256;
    const int m0 = blockIdx.y * 256;
    const int bz = blockIdx.z;

    const int ld = (SEGS == 3) ? 2 * K : K;     // row stride (elements)
    const long long ld64 = (long long)ld * 64;

    const u16* Ab  = A + (long long)bz * sA;
    const u16* Bbp = B + (long long)bz * sB;

    // staging source: thread t -> row (t>>3), 16B slot (t&7)^(row&7)
    const int srow  = tid >> 3;                       // 0..63 within issue
    const int scol8 = ((tid & 7) ^ (srow & 7)) * 8;
    const u16* aBase = Ab  + (long long)(m0 + srow) * ld + scol8;
    const u16* bBase = Bbp + (long long)(n0 + srow) * ld + scol8;

    // ds_read offsets: row*128 + swizzled slot*16 (ks=1 -> ^64)
    const int swz = (lq ^ (lr & 7)) << 4;
    const int aRd = (wm * 128 + lr) * 128 + swz;
    const int bRd = 32768 + (wn * 64 + lr) * 128 + swz;

    f32x4 acc[8][4];
    #pragma unroll
    for (int i = 0; i < 8; ++i)
        #pragma unroll
        for (int j = 0; j < 4; ++j)
            acc[i][j] = (f32x4){0.f, 0.f, 0.f, 0.f};

    const int NT = (SEGS == 3 ? 3 * K : K) / 64;

    // ---- prologue: stage tile 0 into buf0, order A0,A2,B0,B1,B2,B3,A1,A3 ----
    {
        char* nA = lds + tid * 16;
        char* nB = lds + 32768 + tid * 16;
        gload16(aBase,            nA);
        gload16(aBase + 2 * ld64, nA + 16384);
        gload16(bBase,            nB);
        gload16(bBase + ld64,     nB + 8192);
        gload16(bBase + 2 * ld64, nB + 16384);
        gload16(bBase + 3 * ld64, nB + 24576);
        gload16(aBase + ld64,     nA + 8192);
        gload16(aBase + 3 * ld64, nA + 24576);
    }
    asm volatile("s_waitcnt vmcnt(2)" ::: "memory");   // first-6 of tile 0
    __builtin_amdgcn_s_barrier();

    // ---- main: compute tile t from buf[t&1], stage tile t+1 into buf[~] ----
    int kst = 64, seg = 0;                 // k-state of tile being staged
    for (int t = 0; t < NT - 1; ++t) {
        if (SEGS == 3 && kst == K) { kst = 0; ++seg; }
        const u16* aP = aBase + kst + ((SEGS == 3 && seg == 2) ? K : 0);
        const u16* bP = bBase + kst + ((SEGS == 3 && seg == 1) ? K : 0);
        const char* cb = lds + (t & 1) * 65536;
        char* nb = lds + ((t + 1) & 1) * 65536;
        do_tile<true>(cb, nb + tid * 16, nb + 32768 + tid * 16,
                      aP, bP, ld64, aRd, bRd, acc);
        kst += 64;
    }
    do_tile<false>(lds + ((NT - 1) & 1) * 65536, lds, lds,
                   aBase, bBase, ld64, aRd, bRd, acc);

    // ---- epilogue: C/D layout row=(lane>>4)*4+reg, col=lane&15 ----
    if constexpr (EPI == 0) {
        #pragma unroll
        for (int mt = 0; mt < 8; ++mt) {
            const int row = m0 + wm * 128 + mt * 16 + lq * 4;
            #pragma unroll
            for (int nt = 0; nt < 4; ++nt) {
                const int col = n0 + wn * 64 + nt * 16 + lr;
                #pragma unroll
                for (int rg = 0; rg < 4; ++rg)
                    Cf[(long long)bz * sC + (long long)(row + rg) * N + col] =
                        acc[mt][nt][rg];
            }
        }
    } else {
        #pragma unroll
        for (int mt = 0; mt < 8; ++mt) {
            const int row = m0 + wm * 128 + mt * 16 + lq * 4;
            #pragma unroll
            for (int nt = 0; nt < 4; ++nt) {
                const int col = n0 + wn * 64 + nt * 16 + lr;
                #pragma unroll
                for (int rg = 0; rg < 4; ++rg) {
                    const long long base =
                        (long long)bz * sC + (long long)(row + rg) * (2 * N);
                    u16 h, l;
                    split1(acc[mt][nt][rg], h, l);
                    C2[base + col]     = h;
                    C2[base + N + col] = l;
                }
            }
        }
    }
}

// ---------------------------------------------------------------------------
// fp32 [R][1024] -> bf16 [R][2048]  (h in cols 0..1023, l in 1024..2047)
// ---------------------------------------------------------------------------
__global__ __launch_bounds__(256)
void split_rows(const float* __restrict__ in, u16* __restrict__ out)
{
    const long long i = (long long)blockIdx.x * 256 + threadIdx.x; // 8-chunk id
    const long long row = i >> 7;              // 128 chunks / row
    const int c = ((int)i & 127) << 3;
    const float* p = in + row * 1024 + c;
    float4 v0 = *(const float4*)p;
    float4 v1 = *(const float4*)(p + 4);
    float x[8] = {v0.x, v0.y, v0.z, v0.w, v1.x, v1.y, v1.z, v1.w};
    u16x8 h, l;
    #pragma unroll
    for (int j = 0; j < 8; ++j) {
        u16 hh, lo;
        split1(x[j], hh, lo);
        h[j] = hh; l[j] = lo;
    }
    u16* q = out + row * 2048 + c;
    *(u16x8*)q = h;
    *(u16x8*)(q + 1024) = l;
}

// ---------------------------------------------------------------------------
// Transpose fp32 [R][C] -> bf16 [C][R] (hi only). 32x32 tiles.
// ---------------------------------------------------------------------------
__global__ __launch_bounds__(256)
void transpose_h(const float* __restrict__ in, u16* __restrict__ outh,
                 int R, int C, long long sIn, long long sOut)
{
    __shared__ float t[32][33];
    const int bz = blockIdx.z;
    const int c0 = blockIdx.x * 32;
    const int r0 = blockIdx.y * 32;
    const float* inb = in + (long long)bz * sIn;
    const int tid = threadIdx.x;
    #pragma unroll
    for (int i = 0; i < 4; ++i) {
        int e = i * 256 + tid;
        int r = e >> 5, c = e & 31;
        t[r][c] = inb[(long long)(r0 + r) * C + c0 + c];
    }
    __syncthreads();
    #pragma unroll
    for (int i = 0; i < 4; ++i) {
        int e = i * 256 + tid;
        int r = e >> 5, c = e & 31;
        outh[(long long)bz * sOut + (long long)(c0 + r) * R + r0 + c] =
            f2bf(t[c][r]);
    }
}

// ---------------------------------------------------------------------------
// W [D][D] fp32 -> Wt2 [D][2D] bf16: h at [e][d], l at [e][D+d]
// ---------------------------------------------------------------------------
__global__ __launch_bounds__(256)
void transpose_split2(const float* __restrict__ in, u16* __restrict__ out2)
{
    __shared__ float t[32][33];
    const int c0 = blockIdx.x * 32;
    const int r0 = blockIdx.y * 32;
    const int tid = threadIdx.x;
    #pragma unroll
    for (int i = 0; i < 4; ++i) {
        int e = i * 256 + tid;
        int r = e >> 5, c = e & 31;
        t[r][c] = in[(long long)(r0 + r) * D + c0 + c];
    }
    __syncthreads();
    #pragma unroll
    for (int i = 0; i < 4; ++i) {
        int e = i * 256 + tid;
        int r = e >> 5, c = e & 31;
        u16 h, l;
        split1(t[c][r], h, l);
        const long long off = (long long)(c0 + r) * (2 * D) + r0 + c;
        out2[off]     = h;
        out2[off + D] = l;
    }
}

// ---------------------------------------------------------------------------
// Row softmax in place + bf16 copy: one block per row of TK floats.
// ---------------------------------------------------------------------------
__global__ __launch_bounds__(256)
void softmax_kernel(float* __restrict__ S, u16* __restrict__ Sb)
{
    __shared__ float red[4];
    const long long row = blockIdx.x;
    float* p = S + row * (long long)TK;
    const int tid = threadIdx.x;

    float x[8];
    *(float4*)&x[0] = *(const float4*)(p + tid * 8);
    *(float4*)&x[4] = *(const float4*)(p + tid * 8 + 4);

    float mx = x[0];
    #pragma unroll
    for (int i = 1; i < 8; ++i) mx = fmaxf(mx, x[i]);
    #pragma unroll
    for (int off = 32; off > 0; off >>= 1) mx = fmaxf(mx, __shfl_down(mx, off, 64));
    if ((tid & 63) == 0) red[tid >> 6] = mx;
    __syncthreads();
    mx = fmaxf(fmaxf(red[0], red[1]), fmaxf(red[2], red[3]));
    __syncthreads();

    float s = 0.f;
    #pragma unroll
    for (int i = 0; i < 8; ++i) { x[i] = __expf(x[i] - mx); s += x[i]; }
    #pragma unroll
    for (int off = 32; off > 0; off >>= 1) s += __shfl_down(s, off, 64);
    if ((tid & 63) == 0) red[tid >> 6] = s;
    __syncthreads();
    s = red[0] + red[1] + red[2] + red[3];

    const float inv = 1.f / s;
    #pragma unroll
    for (int i = 0; i < 8; ++i) x[i] *= inv;
    *(float4*)(p + tid * 8)     = *(const float4*)&x[0];
    *(float4*)(p + tid * 8 + 4) = *(const float4*)&x[4];

    u16x8 hb;
    #pragma unroll
    for (int i = 0; i < 8; ++i) hb[i] = f2bf(x[i]);
    *(u16x8*)(Sb + row * (long long)TK + tid * 8) = hb;
}

} // anonymous namespace

extern "C" void kernel_launch(void* const* d_in, const int* in_sizes, int n_in,
                              void* d_out, int out_size, void* d_ws, size_t ws_size,
                              hipStream_t stream)
{
    typedef long long ll;
    const float* dec = (const float*)d_in[0];  // [B, TQ, D]
    const float* enc = (const float*)d_in[1];  // [B, TK, D]
    const float* W   = (const float*)d_in[2];  // [D, D]
    // d_in[3] = bias: contributes dec[q].bias, constant along the softmax
    // axis -> cancels exactly in softmax; neither output depends on it.

    float* out     = (float*)d_out;
    float* context = out;                      // [B, TQ, D]
    float* align   = out + (ll)Bb * TQ * D;    // [B, TQ, TK]

    // workspace (u16): dec2 [B][TQ][2D] | keys2 [B][TK][2D] | Wt2 [D][2D]
    u16* dec2   = (u16*)d_ws;
    u16* keys2  = dec2 + (ll)Bb * TQ * 2 * D;
    u16* Wt2    = keys2 + (ll)Bb * TK * 2 * D;
    // scratch aliases (lifetimes verified against launch order):
    u16* enc2   = (u16*)align;   // enc split lives in align region until score
    u16* encT   = dec2;          // [B][D][TK]; dec2 dead after score
    u16* alignb = keys2;         // [B][TQ][TK] bf16; keys2 dead after score

    dim3 blk256(256);
    dim3 blk512(512);

    // 1) dec2 = split(dec)
    split_rows<<<dim3(Bb * TQ * D / 8 / 256), blk256, 0, stream>>>(dec, dec2);
    // 2) enc2 = split(enc)  (scratch in align output region)
    split_rows<<<dim3(Bb * TK * D / 8 / 256), blk256, 0, stream>>>(enc, enc2);
    // 3) Wt2 = split(W^T)
    transpose_split2<<<dim3(D / 32, D / 32, 1), blk256, 0, stream>>>(W, Wt2);
    // 4) keys2 = split(enc @ W)   (bf16x3, split-store epilogue)
    gemm_nt_pipe<3, 1><<<dim3(D / 256, TK / 256, Bb), blk512, 0, stream>>>(
        enc2, Wt2, nullptr, keys2, TK, D, D,
        (ll)TK * 2 * D, 0LL, (ll)TK * 2 * D);
    // 5) score = dec @ keys^T  (bf16x3) -> align region, fp32
    gemm_nt_pipe<3, 0><<<dim3(TK / 256, TQ / 256, Bb), blk512, 0, stream>>>(
        dec2, keys2, align, nullptr, TQ, TK, D,
        (ll)TQ * 2 * D, (ll)TK * 2 * D, (ll)TQ * TK);
    // 6) encT = enc^T bf16 (into dec2 space)
    transpose_h<<<dim3(D / 32, TK / 32, Bb), blk256, 0, stream>>>(
        enc, encT, TK, D, (ll)TK * D, (ll)D * TK);
    // 7) softmax in place + bf16 copy into alignb (keys2 space)
    softmax_kernel<<<dim3(Bb * TQ), blk256, 0, stream>>>(align, alignb);
    // 8) context = align @ enc  (plain bf16)
    gemm_nt_pipe<1, 0><<<dim3(D / 256, TQ / 256, Bb), blk512, 0, stream>>>(
        alignb, encT, context, nullptr, TQ, D, TK,
        (ll)TQ * TK, (ll)D * TK, (ll)TQ * D);
}